// Round 1
// baseline (1653.653 us; speedup 1.0000x reference)
//
#include <hip/hip_runtime.h>
#include <math.h>

#define IN_CH   128
#define HID     128
#define OUT_CH  64
#define NGRAPH  512

// ---------------- degree / norm ----------------

__global__ __launch_bounds__(256) void deg_init_k(float* deg, int n) {
    int i = blockIdx.x * 256 + threadIdx.x;
    if (i < n) deg[i] = 1.0f;               // self loop
}

__global__ __launch_bounds__(256) void deg_count_k(const int* __restrict__ ei, float* deg, int E) {
    int e = blockIdx.x * 256 + threadIdx.x;
    if (e < E) atomicAdd(&deg[ei[E + e]], 1.0f);   // dst row of edge_index
}

__global__ __launch_bounds__(256) void dinv_k(float* deg, int n) {
    int i = blockIdx.x * 256 + threadIdx.x;
    if (i < n) deg[i] = rsqrtf(deg[i]);     // deg >= 1 always (self loop)
}

// ---------------- GEMM: C[nRows x COLS] = A[nRows x 128] @ W[128 x COLS] (+bias) ----------------
// 64 rows per block, 256 threads, K staged in 2 chunks of 64.
// xs padded to stride 65 -> bank = (row + k) % 32, conflict-free across the 4 rows/thread.

template<int COLS, bool BIAS>
__global__ __launch_bounds__(256) void gemm_k(const float* __restrict__ A,
                                              const float* __restrict__ W,
                                              const float* __restrict__ bias,
                                              float* __restrict__ C, int nRows) {
    constexpr int TC = COLS / 16;                 // cols per thread (8 or 4)
    __shared__ float ws[64 * COLS];               // K-chunk x COLS
    __shared__ float xs[64 * 65];                 // rows x K-chunk (padded)
    const int tid = threadIdx.x;
    const int rowBase = blockIdx.x * 64;
    const int tr = tid >> 4;                      // 0..15 -> rows tr*4..tr*4+3
    const int tc = tid & 15;                      // 0..15 -> cols tc*TC..

    float acc[4][TC];
#pragma unroll
    for (int i = 0; i < 4; ++i)
#pragma unroll
        for (int j = 0; j < TC; ++j) acc[i][j] = 0.0f;

    for (int kc = 0; kc < 2; ++kc) {
        // stage W chunk (64 x COLS), coalesced float4
        for (int i = tid; i < 64 * COLS / 4; i += 256) {
            int r = i / (COLS / 4), c = (i % (COLS / 4)) * 4;
            *(float4*)&ws[r * COLS + c] = *(const float4*)&W[(kc * 64 + r) * COLS + c];
        }
        // stage x tile (64 rows x 64 k), scalar LDS writes into padded layout
        for (int i = tid; i < 64 * 16; i += 256) {
            int r = i >> 4, c = (i & 15) * 4;
            float4 v = make_float4(0.f, 0.f, 0.f, 0.f);
            if (rowBase + r < nRows)
                v = *(const float4*)&A[(size_t)(rowBase + r) * 128 + kc * 64 + c];
            xs[r * 65 + c + 0] = v.x; xs[r * 65 + c + 1] = v.y;
            xs[r * 65 + c + 2] = v.z; xs[r * 65 + c + 3] = v.w;
        }
        __syncthreads();
#pragma unroll
        for (int k = 0; k < 64; ++k) {
            float xv[4];
#pragma unroll
            for (int i = 0; i < 4; ++i) xv[i] = xs[(tr * 4 + i) * 65 + k];
            float wv[TC];
#pragma unroll
            for (int j = 0; j < TC; j += 4)
                *(float4*)&wv[j] = *(float4*)&ws[k * COLS + tc * TC + j];
#pragma unroll
            for (int i = 0; i < 4; ++i)
#pragma unroll
                for (int j = 0; j < TC; ++j)
                    acc[i][j] = fmaf(xv[i], wv[j], acc[i][j]);
        }
        __syncthreads();
    }

#pragma unroll
    for (int i = 0; i < 4; ++i) {
        int row = rowBase + tr * 4 + i;
        if (row < nRows) {
#pragma unroll
            for (int j = 0; j < TC; j += 4) {
                float4 v = *(float4*)&acc[i][j];
                if (BIAS) {
                    float4 bv = *(const float4*)&bias[tc * TC + j];
                    v.x += bv.x; v.y += bv.y; v.z += bv.z; v.w += bv.w;
                }
                *(float4*)&C[(size_t)row * COLS + tc * TC + j] = v;
            }
        }
    }
}

// ---------------- aggregation ----------------

// agg[i,:] = h[i,:] * dinv[i]^2   (self-loop contribution, also initializes agg)
__global__ __launch_bounds__(256) void agg_init_k(const float* __restrict__ h,
                                                  const float* __restrict__ dinv,
                                                  float* __restrict__ agg, int n) {
    int t = blockIdx.x * 256 + threadIdx.x;
    if (t >= n * 32) return;
    int i = t >> 5;
    float d = dinv[i]; float s = d * d;
    float4 v = *(const float4*)&h[(size_t)t * 4];
    v.x *= s; v.y *= s; v.z *= s; v.w *= s;
    *(float4*)&agg[(size_t)t * 4] = v;
}

// one wave (64 lanes) per edge, 2 channels/lane; atomic scatter to dst row
__global__ __launch_bounds__(256) void agg_edges_k(const int* __restrict__ ei,
                                                   const float* __restrict__ dinv,
                                                   const float* __restrict__ h,
                                                   float* __restrict__ agg, int E) {
    int e = blockIdx.x * 4 + (threadIdx.x >> 6);
    if (e >= E) return;
    int lane = threadIdx.x & 63;
    int s = ei[e];
    int d = ei[E + e];
    float nr = dinv[s] * dinv[d];
    float2 hv = *(const float2*)&h[(size_t)s * HID + lane * 2];
    atomicAdd(&agg[(size_t)d * HID + lane * 2 + 0], hv.x * nr);
    atomicAdd(&agg[(size_t)d * HID + lane * 2 + 1], hv.y * nr);
}

// in-place: x = relu(x + b)
__global__ __launch_bounds__(256) void bias_relu_k(float* __restrict__ agg,
                                                   const float* __restrict__ b, int n) {
    int t = blockIdx.x * 256 + threadIdx.x;
    if (t >= n * 32) return;
    int c = (t & 31) * 4;
    float4 v = *(float4*)&agg[(size_t)t * 4];
    float4 bv = *(const float4*)&b[c];
    v.x = fmaxf(v.x + bv.x, 0.f); v.y = fmaxf(v.y + bv.y, 0.f);
    v.z = fmaxf(v.z + bv.z, 0.f); v.w = fmaxf(v.w + bv.w, 0.f);
    *(float4*)&agg[(size_t)t * 4] = v;
}

// ---------------- global mean pool (batch is sorted) ----------------

__global__ __launch_bounds__(128) void pool_k(const int* __restrict__ batch,
                                              const float* __restrict__ h,
                                              float* __restrict__ pooled, int n) {
    int g = blockIdx.x;
    __shared__ int sh[2];
    if (threadIdx.x < 2) {
        int target = g + (int)threadIdx.x;    // first index with batch[i] >= target
        int lo = 0, hi = n;
        while (lo < hi) {
            int mid = (lo + hi) >> 1;
            if (batch[mid] < target) lo = mid + 1; else hi = mid;
        }
        sh[threadIdx.x] = lo;
    }
    __syncthreads();
    int lo = sh[0], hi = sh[1];
    float sum = 0.f;
    for (int i = lo; i < hi; ++i) sum += h[(size_t)i * HID + threadIdx.x];
    float cnt = (float)(hi - lo);
    pooled[(size_t)g * HID + threadIdx.x] = sum / fmaxf(cnt, 1.0f);
}

// ---------------- launch ----------------

extern "C" void kernel_launch(void* const* d_in, const int* in_sizes, int n_in,
                              void* d_out, int out_size, void* d_ws, size_t ws_size,
                              hipStream_t stream) {
    const float* x     = (const float*)d_in[0];
    const int*   ei    = (const int*)d_in[1];
    const int*   batch = (const int*)d_in[2];
    const float* W1    = (const float*)d_in[3];
    const float* b1    = (const float*)d_in[4];
    const float* W2    = (const float*)d_in[5];
    const float* b2    = (const float*)d_in[6];
    const float* Wl    = (const float*)d_in[7];
    const float* bl    = (const float*)d_in[8];

    const int N = in_sizes[0] / IN_CH;
    const int E = in_sizes[1] / 2;

    float* out    = (float*)d_out;                     // [N*OUT_CH]
    float* pooled = out + (size_t)N * OUT_CH;          // [NGRAPH*HID]

    // workspace: dinv (N floats) | bufA (N*128) | bufB (N*128)  ~= 52 MB
    char* ws = (char*)d_ws;
    float* dinv = (float*)ws;
    size_t off = (((size_t)N * 4 + 1023) / 1024) * 1024;
    float* bufA = (float*)(ws + off);
    float* bufB = bufA + (size_t)N * HID;

    const int nbN   = (N + 255) / 256;
    const int nbE   = (E + 255) / 256;
    const int nbNC  = (N * 32 + 255) / 256;   // N*128/4 float4s
    const int nbEdg = (E + 3) / 4;            // 4 edges per 256-thread block
    const int gb    = (N + 63) / 64;          // gemm blocks

    deg_init_k <<<nbN, 256, 0, stream>>>(dinv, N);
    deg_count_k<<<nbE, 256, 0, stream>>>(ei, dinv, E);
    dinv_k     <<<nbN, 256, 0, stream>>>(dinv, N);

    // conv1: h1 = x @ W1 ; agg = Ahat*h1 ; relu(+b1)
    gemm_k<HID, false><<<gb, 256, 0, stream>>>(x, W1, nullptr, bufA, N);
    agg_init_k <<<nbNC,  256, 0, stream>>>(bufA, dinv, bufB, N);
    agg_edges_k<<<nbEdg, 256, 0, stream>>>(ei, dinv, bufA, bufB, E);
    bias_relu_k<<<nbNC,  256, 0, stream>>>(bufB, b1, N);

    // conv2
    gemm_k<HID, false><<<gb, 256, 0, stream>>>(bufB, W2, nullptr, bufA, N);
    agg_init_k <<<nbNC,  256, 0, stream>>>(bufA, dinv, bufB, N);
    agg_edges_k<<<nbEdg, 256, 0, stream>>>(ei, dinv, bufA, bufB, E);
    bias_relu_k<<<nbNC,  256, 0, stream>>>(bufB, b2, N);

    // out = h2 @ Wl + bl  ;  pooled = segment-mean(h2, batch)
    gemm_k<OUT_CH, true><<<gb, 256, 0, stream>>>(bufB, Wl, bl, out, N);
    pool_k<<<NGRAPH, 128, 0, stream>>>(batch, bufB, pooled, N);
}

// Round 2
// 595.577 us; speedup vs baseline: 2.7766x; 2.7766x over previous
//
#include <hip/hip_runtime.h>
#include <math.h>

#define IN_CH   128
#define HID     128
#define OUT_CH  64
#define NGRAPH  512

// ---------------- CSR build ----------------

__global__ __launch_bounds__(256) void cnt_init_k(int* cnt, int n) {
    int i = blockIdx.x * 256 + threadIdx.x;
    if (i < n) cnt[i] = 0;
}

__global__ __launch_bounds__(256) void count_k(const int* __restrict__ ei, int* cnt, int E) {
    int e = blockIdx.x * 256 + threadIdx.x;
    if (e < E) atomicAdd(&cnt[ei[E + e]], 1);     // in-degree of dst (edges only)
}

__global__ __launch_bounds__(256) void dinv_k(const int* __restrict__ cnt, float* dinv, int n) {
    int i = blockIdx.x * 256 + threadIdx.x;
    if (i < n) dinv[i] = rsqrtf((float)cnt[i] + 1.0f);   // +1 self loop
}

// exclusive scan of cnt -> rowptr[0..n], cursor copy; single block of 1024
__global__ __launch_bounds__(1024) void scan_k(const int* __restrict__ cnt,
                                               int* __restrict__ rowptr,
                                               int* __restrict__ cursor, int n) {
    __shared__ int part[1024];
    const int t = threadIdx.x;
    const int chunk = (n + 1023) / 1024;
    const int lo = t * chunk, hi = min(lo + chunk, n);
    int s = 0;
    for (int i = lo; i < hi; ++i) s += cnt[i];
    part[t] = s;
    __syncthreads();
    for (int off = 1; off < 1024; off <<= 1) {    // Hillis-Steele inclusive
        int v = (t >= off) ? part[t - off] : 0;
        __syncthreads();
        part[t] += v;
        __syncthreads();
    }
    int run = (t == 0) ? 0 : part[t - 1];
    for (int i = lo; i < hi; ++i) {
        rowptr[i] = run; cursor[i] = run;
        run += cnt[i];
    }
    if (t == 1023) rowptr[n] = run;               // == E
}

// bucket edges by dst: ebuf[pos] = (src, norm)
__global__ __launch_bounds__(256) void scatter_k(const int* __restrict__ ei,
                                                 const float* __restrict__ dinv,
                                                 int* cursor, int2* __restrict__ ebuf, int E) {
    int e = blockIdx.x * 256 + threadIdx.x;
    if (e >= E) return;
    int s = ei[e], d = ei[E + e];
    int pos = atomicAdd(&cursor[d], 1);
    ebuf[pos] = make_int2(s, __float_as_int(dinv[s] * dinv[d]));
}

// ---------------- GEMM: C[nRows x COLS] = A[nRows x 128] @ W[128 x COLS] (+bias) ----------------

template<int COLS, bool BIAS>
__global__ __launch_bounds__(256) void gemm_k(const float* __restrict__ A,
                                              const float* __restrict__ W,
                                              const float* __restrict__ bias,
                                              float* __restrict__ C, int nRows) {
    constexpr int TC = COLS / 16;
    __shared__ float ws[64 * COLS];
    __shared__ float xs[64 * 65];
    const int tid = threadIdx.x;
    const int rowBase = blockIdx.x * 64;
    const int tr = tid >> 4;
    const int tc = tid & 15;

    float acc[4][TC];
#pragma unroll
    for (int i = 0; i < 4; ++i)
#pragma unroll
        for (int j = 0; j < TC; ++j) acc[i][j] = 0.0f;

    for (int kc = 0; kc < 2; ++kc) {
        for (int i = tid; i < 64 * COLS / 4; i += 256) {
            int r = i / (COLS / 4), c = (i % (COLS / 4)) * 4;
            *(float4*)&ws[r * COLS + c] = *(const float4*)&W[(kc * 64 + r) * COLS + c];
        }
        for (int i = tid; i < 64 * 16; i += 256) {
            int r = i >> 4, c = (i & 15) * 4;
            float4 v = make_float4(0.f, 0.f, 0.f, 0.f);
            if (rowBase + r < nRows)
                v = *(const float4*)&A[(size_t)(rowBase + r) * 128 + kc * 64 + c];
            xs[r * 65 + c + 0] = v.x; xs[r * 65 + c + 1] = v.y;
            xs[r * 65 + c + 2] = v.z; xs[r * 65 + c + 3] = v.w;
        }
        __syncthreads();
#pragma unroll
        for (int k = 0; k < 64; ++k) {
            float xv[4];
#pragma unroll
            for (int i = 0; i < 4; ++i) xv[i] = xs[(tr * 4 + i) * 65 + k];
            float wv[TC];
#pragma unroll
            for (int j = 0; j < TC; j += 4)
                *(float4*)&wv[j] = *(float4*)&ws[k * COLS + tc * TC + j];
#pragma unroll
            for (int i = 0; i < 4; ++i)
#pragma unroll
                for (int j = 0; j < TC; ++j)
                    acc[i][j] = fmaf(xv[i], wv[j], acc[i][j]);
        }
        __syncthreads();
    }

#pragma unroll
    for (int i = 0; i < 4; ++i) {
        int row = rowBase + tr * 4 + i;
        if (row < nRows) {
#pragma unroll
            for (int j = 0; j < TC; j += 4) {
                float4 v = *(float4*)&acc[i][j];
                if (BIAS) {
                    float4 bv = *(const float4*)&bias[tc * TC + j];
                    v.x += bv.x; v.y += bv.y; v.z += bv.z; v.w += bv.w;
                }
                *(float4*)&C[(size_t)row * COLS + tc * TC + j] = v;
            }
        }
    }
}

// ---------------- fused gather-aggregate + self-loop + bias + relu ----------------
// one wave per dst node, 2 channels/lane; no atomics.

__global__ __launch_bounds__(256) void gather_k(const int* __restrict__ rowptr,
                                                const int2* __restrict__ ebuf,
                                                const float* __restrict__ dinv,
                                                const float* __restrict__ h,
                                                const float* __restrict__ bias,
                                                float* __restrict__ out, int n) {
    int node = blockIdx.x * 4 + (threadIdx.x >> 6);
    if (node >= n) return;
    int lane = threadIdx.x & 63;
    float d = dinv[node];
    float2 acc = *(const float2*)&h[(size_t)node * HID + lane * 2];   // self loop
    float s2 = d * d;
    acc.x *= s2; acc.y *= s2;

    int j = rowptr[node], end = rowptr[node + 1];
    for (; j + 1 < end; j += 2) {                 // 2-deep to keep gathers in flight
        int2 e0 = ebuf[j], e1 = ebuf[j + 1];
        float2 h0 = *(const float2*)&h[(size_t)e0.x * HID + lane * 2];
        float2 h1 = *(const float2*)&h[(size_t)e1.x * HID + lane * 2];
        float w0 = __int_as_float(e0.y), w1 = __int_as_float(e1.y);
        acc.x = fmaf(h0.x, w0, acc.x); acc.y = fmaf(h0.y, w0, acc.y);
        acc.x = fmaf(h1.x, w1, acc.x); acc.y = fmaf(h1.y, w1, acc.y);
    }
    if (j < end) {
        int2 e0 = ebuf[j];
        float2 h0 = *(const float2*)&h[(size_t)e0.x * HID + lane * 2];
        float w0 = __int_as_float(e0.y);
        acc.x = fmaf(h0.x, w0, acc.x); acc.y = fmaf(h0.y, w0, acc.y);
    }

    float2 bv = *(const float2*)&bias[lane * 2];
    acc.x = fmaxf(acc.x + bv.x, 0.f);
    acc.y = fmaxf(acc.y + bv.y, 0.f);
    *(float2*)&out[(size_t)node * HID + lane * 2] = acc;
}

// ---------------- global mean pool (batch sorted) ----------------

__global__ __launch_bounds__(128) void pool_k(const int* __restrict__ batch,
                                              const float* __restrict__ h,
                                              float* __restrict__ pooled, int n) {
    int g = blockIdx.x;
    __shared__ int sh[2];
    if (threadIdx.x < 2) {
        int target = g + (int)threadIdx.x;
        int lo = 0, hi = n;
        while (lo < hi) {
            int mid = (lo + hi) >> 1;
            if (batch[mid] < target) lo = mid + 1; else hi = mid;
        }
        sh[threadIdx.x] = lo;
    }
    __syncthreads();
    int lo = sh[0], hi = sh[1];
    float sum = 0.f;
    for (int i = lo; i < hi; ++i) sum += h[(size_t)i * HID + threadIdx.x];
    float cnt = (float)(hi - lo);
    pooled[(size_t)g * HID + threadIdx.x] = sum / fmaxf(cnt, 1.0f);
}

// ---------------- launch ----------------

extern "C" void kernel_launch(void* const* d_in, const int* in_sizes, int n_in,
                              void* d_out, int out_size, void* d_ws, size_t ws_size,
                              hipStream_t stream) {
    const float* x     = (const float*)d_in[0];
    const int*   ei    = (const int*)d_in[1];
    const int*   batch = (const int*)d_in[2];
    const float* W1    = (const float*)d_in[3];
    const float* b1    = (const float*)d_in[4];
    const float* W2    = (const float*)d_in[5];
    const float* b2    = (const float*)d_in[6];
    const float* Wl    = (const float*)d_in[7];
    const float* bl    = (const float*)d_in[8];

    const int N = in_sizes[0] / IN_CH;
    const int E = in_sizes[1] / 2;

    float* out    = (float*)d_out;
    float* pooled = out + (size_t)N * OUT_CH;

    // ws layout (16B aligned blocks):
    // dinv[N] | cnt[N] | rowptr[N+1] | cursor[N] | ebuf[E int2] | bufA[N*128] | bufB[N*128]
    char* w = (char*)d_ws;
    auto align16 = [](size_t s) { return (s + 15) & ~(size_t)15; };
    float* dinv   = (float*)w;                 w += align16((size_t)N * 4);
    int*   cnt    = (int*)w;                   w += align16((size_t)N * 4);
    int*   rowptr = (int*)w;                   w += align16((size_t)(N + 1) * 4);
    int*   cursor = (int*)w;                   w += align16((size_t)N * 4);
    int2*  ebuf   = (int2*)w;                  w += align16((size_t)E * 8);
    float* bufA   = (float*)w;                 w += align16((size_t)N * HID * 4);
    float* bufB   = (float*)w;

    const int nbN = (N + 255) / 256;
    const int nbE = (E + 255) / 256;
    const int nbG = (N + 3) / 4;               // gather: 4 nodes (waves) per block
    const int gb  = (N + 63) / 64;             // gemm blocks

    // CSR build (once, reused by both convs)
    cnt_init_k<<<nbN, 256, 0, stream>>>(cnt, N);
    count_k   <<<nbE, 256, 0, stream>>>(ei, cnt, E);
    dinv_k    <<<nbN, 256, 0, stream>>>(cnt, dinv, N);
    scan_k    <<<1, 1024, 0, stream>>>(cnt, rowptr, cursor, N);
    scatter_k <<<nbE, 256, 0, stream>>>(ei, dinv, cursor, ebuf, E);

    // conv1
    gemm_k<HID, false><<<gb, 256, 0, stream>>>(x, W1, nullptr, bufA, N);
    gather_k<<<nbG, 256, 0, stream>>>(rowptr, ebuf, dinv, bufA, b1, bufB, N);

    // conv2
    gemm_k<HID, false><<<gb, 256, 0, stream>>>(bufB, W2, nullptr, bufA, N);
    gather_k<<<nbG, 256, 0, stream>>>(rowptr, ebuf, dinv, bufA, b2, bufB, N);

    // head
    gemm_k<OUT_CH, true><<<gb, 256, 0, stream>>>(bufB, Wl, bl, out, N);
    pool_k<<<NGRAPH, 128, 0, stream>>>(batch, bufB, pooled, N);
}

// Round 4
// 491.702 us; speedup vs baseline: 3.3631x; 1.2113x over previous
//
#include <hip/hip_runtime.h>
#include <math.h>

#define IN_CH   128
#define HID     128
#define OUT_CH  64
#define NGRAPH  512

// ---------------- CSR build ----------------

__global__ __launch_bounds__(256) void cnt_init_k(int* cnt, int n) {
    int i = blockIdx.x * 256 + threadIdx.x;
    if (i < n) cnt[i] = 0;
}

__global__ __launch_bounds__(256) void count_k(const int* __restrict__ ei, int* cnt, int E) {
    int e = blockIdx.x * 256 + threadIdx.x;
    if (e < E) atomicAdd(&cnt[ei[E + e]], 1);     // in-degree of dst (edges only)
}

__global__ __launch_bounds__(256) void dinv_k(const int* __restrict__ cnt, float* dinv, int n) {
    int i = blockIdx.x * 256 + threadIdx.x;
    if (i < n) dinv[i] = rsqrtf((float)cnt[i] + 1.0f);   // +1 self loop
}

// ---- hierarchical scan: partials -> scan partials -> rescan+offset ----

__global__ __launch_bounds__(256) void scan_part_k(const int* __restrict__ cnt,
                                                   int* __restrict__ bsum, int n) {
    __shared__ int red[256];
    int i = blockIdx.x * 256 + threadIdx.x;
    red[threadIdx.x] = (i < n) ? cnt[i] : 0;
    __syncthreads();
    for (int off = 128; off > 0; off >>= 1) {
        if (threadIdx.x < off) red[threadIdx.x] += red[threadIdx.x + off];
        __syncthreads();
    }
    if (threadIdx.x == 0) bsum[blockIdx.x] = red[0];
}

// single block; nb <= 256 (N <= 65536)
__global__ __launch_bounds__(256) void scan_top_k(const int* __restrict__ bsum,
                                                  int* __restrict__ boff, int nb) {
    __shared__ int sh[256];
    int t = threadIdx.x;
    int v = (t < nb) ? bsum[t] : 0;
    sh[t] = v;
    __syncthreads();
    for (int off = 1; off < 256; off <<= 1) {
        int u = (t >= off) ? sh[t - off] : 0;
        __syncthreads();
        sh[t] += u;
        __syncthreads();
    }
    if (t < nb) boff[t] = sh[t] - v;              // exclusive
}

__global__ __launch_bounds__(256) void scan_down_k(const int* __restrict__ cnt,
                                                   const int* __restrict__ boff,
                                                   int* __restrict__ rowptr,
                                                   int* __restrict__ cursor, int n) {
    __shared__ int sh[256];
    int i = blockIdx.x * 256 + threadIdx.x;
    int t = threadIdx.x;
    int v = (i < n) ? cnt[i] : 0;
    sh[t] = v;
    __syncthreads();
    for (int off = 1; off < 256; off <<= 1) {
        int u = (t >= off) ? sh[t - off] : 0;
        __syncthreads();
        sh[t] += u;
        __syncthreads();
    }
    if (i < n) {
        int o = boff[blockIdx.x] + sh[t] - v;     // exclusive prefix
        rowptr[i] = o; cursor[i] = o;
        if (i == n - 1) rowptr[n] = o + v;        // == E
    }
}

// bucket edges by dst: ebuf[pos] = (src, norm)
__global__ __launch_bounds__(256) void scatter_k(const int* __restrict__ ei,
                                                 const float* __restrict__ dinv,
                                                 int* cursor, int2* __restrict__ ebuf, int E) {
    int e = blockIdx.x * 256 + threadIdx.x;
    if (e >= E) return;
    int s = ei[e], d = ei[E + e];
    int pos = atomicAdd(&cursor[d], 1);
    ebuf[pos] = make_int2(s, __float_as_int(dinv[s] * dinv[d]));
}

// ---------------- GEMM: C[nRows x COLS] = A[nRows x 128] @ W[128 x COLS] (+bias) ----------------

template<int COLS, bool BIAS>
__global__ __launch_bounds__(256) void gemm_k(const float* __restrict__ A,
                                              const float* __restrict__ W,
                                              const float* __restrict__ bias,
                                              float* __restrict__ C, int nRows) {
    constexpr int TC = COLS / 16;
    __shared__ float ws[64 * COLS];
    __shared__ float xs[64 * 65];
    const int tid = threadIdx.x;
    const int rowBase = blockIdx.x * 64;
    const int tr = tid >> 4;
    const int tc = tid & 15;

    float acc[4][TC];
#pragma unroll
    for (int i = 0; i < 4; ++i)
#pragma unroll
        for (int j = 0; j < TC; ++j) acc[i][j] = 0.0f;

    for (int kc = 0; kc < 2; ++kc) {
        for (int i = tid; i < 64 * COLS / 4; i += 256) {
            int r = i / (COLS / 4), c = (i % (COLS / 4)) * 4;
            *(float4*)&ws[r * COLS + c] = *(const float4*)&W[(kc * 64 + r) * COLS + c];
        }
        for (int i = tid; i < 64 * 16; i += 256) {
            int r = i >> 4, c = (i & 15) * 4;
            float4 v = make_float4(0.f, 0.f, 0.f, 0.f);
            if (rowBase + r < nRows)
                v = *(const float4*)&A[(size_t)(rowBase + r) * 128 + kc * 64 + c];
            xs[r * 65 + c + 0] = v.x; xs[r * 65 + c + 1] = v.y;
            xs[r * 65 + c + 2] = v.z; xs[r * 65 + c + 3] = v.w;
        }
        __syncthreads();
#pragma unroll
        for (int k = 0; k < 64; ++k) {
            float xv[4];
#pragma unroll
            for (int i = 0; i < 4; ++i) xv[i] = xs[(tr * 4 + i) * 65 + k];
            float wv[TC];
#pragma unroll
            for (int j = 0; j < TC; j += 4)
                *(float4*)&wv[j] = *(float4*)&ws[k * COLS + tc * TC + j];
#pragma unroll
            for (int i = 0; i < 4; ++i)
#pragma unroll
                for (int j = 0; j < TC; ++j)
                    acc[i][j] = fmaf(xv[i], wv[j], acc[i][j]);
        }
        __syncthreads();
    }

#pragma unroll
    for (int i = 0; i < 4; ++i) {
        int row = rowBase + tr * 4 + i;
        if (row < nRows) {
#pragma unroll
            for (int j = 0; j < TC; j += 4) {
                float4 v = *(float4*)&acc[i][j];
                if (BIAS) {
                    float4 bv = *(const float4*)&bias[tc * TC + j];
                    v.x += bv.x; v.y += bv.y; v.z += bv.z; v.w += bv.w;
                }
                *(float4*)&C[(size_t)row * COLS + tc * TC + j] = v;
            }
        }
    }
}

// ---------------- fused gather-aggregate + self-loop + bias + relu ----------------
// 32 lanes per dst node, float4 (4 ch) per lane, 4-edge-deep unroll; no atomics.

__global__ __launch_bounds__(256) void gather_k(const int* __restrict__ rowptr,
                                                const int2* __restrict__ ebuf,
                                                const float* __restrict__ dinv,
                                                const float* __restrict__ h,
                                                const float* __restrict__ bias,
                                                float* __restrict__ out, int n) {
    int node = blockIdx.x * 8 + (threadIdx.x >> 5);
    if (node >= n) return;
    int c = (threadIdx.x & 31) * 4;
    float d = dinv[node];
    float s2 = d * d;
    float4 acc = *(const float4*)&h[(size_t)node * HID + c];   // self loop
    acc.x *= s2; acc.y *= s2; acc.z *= s2; acc.w *= s2;

    int j = rowptr[node], end = rowptr[node + 1];
    for (; j + 3 < end; j += 4) {
        int2 e0 = ebuf[j], e1 = ebuf[j + 1], e2 = ebuf[j + 2], e3 = ebuf[j + 3];
        float4 h0 = *(const float4*)&h[(size_t)e0.x * HID + c];
        float4 h1 = *(const float4*)&h[(size_t)e1.x * HID + c];
        float4 h2 = *(const float4*)&h[(size_t)e2.x * HID + c];
        float4 h3 = *(const float4*)&h[(size_t)e3.x * HID + c];
        float w0 = __int_as_float(e0.y), w1 = __int_as_float(e1.y);
        float w2 = __int_as_float(e2.y), w3 = __int_as_float(e3.y);
        acc.x = fmaf(h0.x, w0, acc.x); acc.y = fmaf(h0.y, w0, acc.y);
        acc.z = fmaf(h0.z, w0, acc.z); acc.w = fmaf(h0.w, w0, acc.w);
        acc.x = fmaf(h1.x, w1, acc.x); acc.y = fmaf(h1.y, w1, acc.y);
        acc.z = fmaf(h1.z, w1, acc.z); acc.w = fmaf(h1.w, w1, acc.w);
        acc.x = fmaf(h2.x, w2, acc.x); acc.y = fmaf(h2.y, w2, acc.y);
        acc.z = fmaf(h2.z, w2, acc.z); acc.w = fmaf(h2.w, w2, acc.w);
        acc.x = fmaf(h3.x, w3, acc.x); acc.y = fmaf(h3.y, w3, acc.y);
        acc.z = fmaf(h3.z, w3, acc.z); acc.w = fmaf(h3.w, w3, acc.w);
    }
    for (; j < end; ++j) {
        int2 e0 = ebuf[j];
        float4 h0 = *(const float4*)&h[(size_t)e0.x * HID + c];
        float w0 = __int_as_float(e0.y);
        acc.x = fmaf(h0.x, w0, acc.x); acc.y = fmaf(h0.y, w0, acc.y);
        acc.z = fmaf(h0.z, w0, acc.z); acc.w = fmaf(h0.w, w0, acc.w);
    }

    float4 bv = *(const float4*)&bias[c];
    acc.x = fmaxf(acc.x + bv.x, 0.f);
    acc.y = fmaxf(acc.y + bv.y, 0.f);
    acc.z = fmaxf(acc.z + bv.z, 0.f);
    acc.w = fmaxf(acc.w + bv.w, 0.f);
    *(float4*)&out[(size_t)node * HID + c] = acc;
}

// ---------------- global mean pool (batch sorted) ----------------

__global__ __launch_bounds__(128) void pool_k(const int* __restrict__ batch,
                                              const float* __restrict__ h,
                                              float* __restrict__ pooled, int n) {
    int g = blockIdx.x;
    __shared__ int sh[2];
    if (threadIdx.x < 2) {
        int target = g + (int)threadIdx.x;
        int lo = 0, hi = n;
        while (lo < hi) {
            int mid = (lo + hi) >> 1;
            if (batch[mid] < target) lo = mid + 1; else hi = mid;
        }
        sh[threadIdx.x] = lo;
    }
    __syncthreads();
    int lo = sh[0], hi = sh[1];
    float sum = 0.f;
    for (int i = lo; i < hi; ++i) sum += h[(size_t)i * HID + threadIdx.x];
    float cnt = (float)(hi - lo);
    pooled[(size_t)g * HID + threadIdx.x] = sum / fmaxf(cnt, 1.0f);
}

// ---------------- launch ----------------

extern "C" void kernel_launch(void* const* d_in, const int* in_sizes, int n_in,
                              void* d_out, int out_size, void* d_ws, size_t ws_size,
                              hipStream_t stream) {
    const float* x     = (const float*)d_in[0];
    const int*   ei    = (const int*)d_in[1];
    const int*   batch = (const int*)d_in[2];
    const float* W1    = (const float*)d_in[3];
    const float* b1    = (const float*)d_in[4];
    const float* W2    = (const float*)d_in[5];
    const float* b2    = (const float*)d_in[6];
    const float* Wl    = (const float*)d_in[7];
    const float* bl    = (const float*)d_in[8];

    const int N = in_sizes[0] / IN_CH;
    const int E = in_sizes[1] / 2;

    float* out    = (float*)d_out;
    float* pooled = out + (size_t)N * OUT_CH;

    // ws layout: dinv[N] | cnt[N] | rowptr[N+1] | cursor[N] | bsum[256] | boff[256]
    //            | ebuf[E int2] | bufA[N*128] | bufB[N*128]
    char* w = (char*)d_ws;
    auto align16 = [](size_t s) { return (s + 15) & ~(size_t)15; };
    float* dinv   = (float*)w;                 w += align16((size_t)N * 4);
    int*   cnt    = (int*)w;                   w += align16((size_t)N * 4);
    int*   rowptr = (int*)w;                   w += align16((size_t)(N + 1) * 4);
    int*   cursor = (int*)w;                   w += align16((size_t)N * 4);
    int*   bsum   = (int*)w;                   w += align16(256 * 4);
    int*   boff   = (int*)w;                   w += align16(256 * 4);
    int2*  ebuf   = (int2*)w;                  w += align16((size_t)E * 8);
    float* bufA   = (float*)w;                 w += align16((size_t)N * HID * 4);
    float* bufB   = (float*)w;

    const int nbN = (N + 255) / 256;           // 196 for N=50000 (<=256 for scan_top)
    const int nbE = (E + 255) / 256;
    const int nbG = (N + 7) / 8;               // gather: 8 nodes (half-waves) per block
    const int gb  = (N + 63) / 64;             // gemm blocks

    // CSR build (once, reused by both convs)
    cnt_init_k <<<nbN, 256, 0, stream>>>(cnt, N);
    count_k    <<<nbE, 256, 0, stream>>>(ei, cnt, E);
    dinv_k     <<<nbN, 256, 0, stream>>>(cnt, dinv, N);
    scan_part_k<<<nbN, 256, 0, stream>>>(cnt, bsum, N);
    scan_top_k <<<1,   256, 0, stream>>>(bsum, boff, nbN);
    scan_down_k<<<nbN, 256, 0, stream>>>(cnt, boff, rowptr, cursor, N);
    scatter_k  <<<nbE, 256, 0, stream>>>(ei, dinv, cursor, ebuf, E);

    // conv1
    gemm_k<HID, false><<<gb, 256, 0, stream>>>(x, W1, nullptr, bufA, N);
    gather_k<<<nbG, 256, 0, stream>>>(rowptr, ebuf, dinv, bufA, b1, bufB, N);

    // conv2
    gemm_k<HID, false><<<gb, 256, 0, stream>>>(bufB, W2, nullptr, bufA, N);
    gather_k<<<nbG, 256, 0, stream>>>(rowptr, ebuf, dinv, bufA, b2, bufB, N);

    // head
    gemm_k<OUT_CH, true><<<gb, 256, 0, stream>>>(bufB, Wl, bl, out, N);
    pool_k<<<NGRAPH, 128, 0, stream>>>(batch, bufB, pooled, N);
}

// Round 6
// 435.398 us; speedup vs baseline: 3.7980x; 1.1293x over previous
//
#include <hip/hip_runtime.h>
#include <math.h>

#define IN_CH   128
#define HID     128
#define OUT_CH  64
#define NGRAPH  512

// ---------------- CSR build ----------------

__global__ __launch_bounds__(256) void cnt_init_k(int* cnt, int n) {
    int i = blockIdx.x * 256 + threadIdx.x;
    if (i < n) cnt[i] = 0;
}

__global__ __launch_bounds__(256) void count_k(const int* __restrict__ ei, int* cnt, int E) {
    int e = blockIdx.x * 256 + threadIdx.x;
    if (e < E) atomicAdd(&cnt[ei[E + e]], 1);     // in-degree of dst (edges only)
}

__global__ __launch_bounds__(256) void dinv_k(const int* __restrict__ cnt, float* dinv, int n) {
    int i = blockIdx.x * 256 + threadIdx.x;
    if (i < n) dinv[i] = rsqrtf((float)cnt[i] + 1.0f);   // +1 self loop
}

// ---- hierarchical scan: partials -> scan partials -> rescan+offset ----

__global__ __launch_bounds__(256) void scan_part_k(const int* __restrict__ cnt,
                                                   int* __restrict__ bsum, int n) {
    __shared__ int red[256];
    int i = blockIdx.x * 256 + threadIdx.x;
    red[threadIdx.x] = (i < n) ? cnt[i] : 0;
    __syncthreads();
    for (int off = 128; off > 0; off >>= 1) {
        if (threadIdx.x < off) red[threadIdx.x] += red[threadIdx.x + off];
        __syncthreads();
    }
    if (threadIdx.x == 0) bsum[blockIdx.x] = red[0];
}

// single block; nb <= 256 (N <= 65536)
__global__ __launch_bounds__(256) void scan_top_k(const int* __restrict__ bsum,
                                                  int* __restrict__ boff, int nb) {
    __shared__ int sh[256];
    int t = threadIdx.x;
    int v = (t < nb) ? bsum[t] : 0;
    sh[t] = v;
    __syncthreads();
    for (int off = 1; off < 256; off <<= 1) {
        int u = (t >= off) ? sh[t - off] : 0;
        __syncthreads();
        sh[t] += u;
        __syncthreads();
    }
    if (t < nb) boff[t] = sh[t] - v;              // exclusive
}

__global__ __launch_bounds__(256) void scan_down_k(const int* __restrict__ cnt,
                                                   const int* __restrict__ boff,
                                                   int* __restrict__ rowptr,
                                                   int* __restrict__ cursor, int n) {
    __shared__ int sh[256];
    int i = blockIdx.x * 256 + threadIdx.x;
    int t = threadIdx.x;
    int v = (i < n) ? cnt[i] : 0;
    sh[t] = v;
    __syncthreads();
    for (int off = 1; off < 256; off <<= 1) {
        int u = (t >= off) ? sh[t - off] : 0;
        __syncthreads();
        sh[t] += u;
        __syncthreads();
    }
    if (i < n) {
        int o = boff[blockIdx.x] + sh[t] - v;     // exclusive prefix
        rowptr[i] = o; cursor[i] = o;
        if (i == n - 1) rowptr[n] = o + v;        // == E
    }
}

// bucket edges by dst: ebuf[pos] = (src, norm)
__global__ __launch_bounds__(256) void scatter_k(const int* __restrict__ ei,
                                                 const float* __restrict__ dinv,
                                                 int* cursor, int2* __restrict__ ebuf, int E) {
    int e = blockIdx.x * 256 + threadIdx.x;
    if (e >= E) return;
    int s = ei[e], d = ei[E + e];
    int pos = atomicAdd(&cursor[d], 1);
    ebuf[pos] = make_int2(s, __float_as_int(dinv[s] * dinv[d]));
}

// ---------------- GEMM: C[nRows x COLS] = A[nRows x 128] @ W[128 x COLS] (+bias) ----------------
// 64 rows/block, 256 threads. Thread (tr,tc) owns rows tr*4..+3, cols {g*64 + tc*4..+3}.
// ws b128 read: 16 tc-lanes cover 64 consecutive floats -> 2 lanes/bank -> conflict-free.
// unroll capped at 4 to keep VGPR < 128.

template<int COLS, bool BIAS>
__global__ __launch_bounds__(256) void gemm_k(const float* __restrict__ A,
                                              const float* __restrict__ W,
                                              const float* __restrict__ bias,
                                              float* __restrict__ C, int nRows) {
    constexpr int NG = COLS / 64;                 // groups of 64 cols (2 or 1)
    __shared__ float ws[64 * COLS];               // K-chunk x COLS
    __shared__ float xs[64 * 65];                 // rows x K-chunk (padded)
    const int tid = threadIdx.x;
    const int rowBase = blockIdx.x * 64;
    const int tr = tid >> 4;                      // rows tr*4..tr*4+3
    const int tc = tid & 15;                      // cols g*64 + tc*4

    float acc[4][NG][4];
#pragma unroll
    for (int i = 0; i < 4; ++i)
#pragma unroll
        for (int g = 0; g < NG; ++g)
#pragma unroll
            for (int j = 0; j < 4; ++j) acc[i][g][j] = 0.0f;

    for (int kc = 0; kc < 2; ++kc) {
        for (int i = tid; i < 64 * COLS / 4; i += 256) {
            int r = i / (COLS / 4), c = (i % (COLS / 4)) * 4;
            *(float4*)&ws[r * COLS + c] = *(const float4*)&W[(kc * 64 + r) * COLS + c];
        }
        for (int i = tid; i < 64 * 16; i += 256) {
            int r = i >> 4, c = (i & 15) * 4;
            float4 v = make_float4(0.f, 0.f, 0.f, 0.f);
            if (rowBase + r < nRows)
                v = *(const float4*)&A[(size_t)(rowBase + r) * 128 + kc * 64 + c];
            xs[r * 65 + c + 0] = v.x; xs[r * 65 + c + 1] = v.y;
            xs[r * 65 + c + 2] = v.z; xs[r * 65 + c + 3] = v.w;
        }
        __syncthreads();
#pragma unroll 4
        for (int k = 0; k < 64; ++k) {
            float xv[4];
#pragma unroll
            for (int i = 0; i < 4; ++i) xv[i] = xs[(tr * 4 + i) * 65 + k];
            float wv[NG][4];
#pragma unroll
            for (int g = 0; g < NG; ++g)
                *(float4*)&wv[g][0] = *(const float4*)&ws[k * COLS + g * 64 + tc * 4];
#pragma unroll
            for (int i = 0; i < 4; ++i)
#pragma unroll
                for (int g = 0; g < NG; ++g)
#pragma unroll
                    for (int j = 0; j < 4; ++j)
                        acc[i][g][j] = fmaf(xv[i], wv[g][j], acc[i][g][j]);
        }
        __syncthreads();
    }

#pragma unroll
    for (int i = 0; i < 4; ++i) {
        int row = rowBase + tr * 4 + i;
        if (row < nRows) {
#pragma unroll
            for (int g = 0; g < NG; ++g) {
                float4 v = *(float4*)&acc[i][g][0];
                if (BIAS) {
                    float4 bv = *(const float4*)&bias[g * 64 + tc * 4];
                    v.x += bv.x; v.y += bv.y; v.z += bv.z; v.w += bv.w;
                }
                *(float4*)&C[(size_t)row * COLS + g * 64 + tc * 4] = v;
            }
        }
    }
}

// ---------------- fused gather-aggregate + self-loop + bias + relu ----------------
// 32 lanes per dst node, float4 (4 ch) per lane, 8-edge-deep unroll; no atomics.

__global__ __launch_bounds__(256) void gather_k(const int* __restrict__ rowptr,
                                                const int2* __restrict__ ebuf,
                                                const float* __restrict__ dinv,
                                                const float* __restrict__ h,
                                                const float* __restrict__ bias,
                                                float* __restrict__ out, int n) {
    int node = blockIdx.x * 8 + (threadIdx.x >> 5);
    if (node >= n) return;
    int c = (threadIdx.x & 31) * 4;
    float d = dinv[node];
    float s2 = d * d;
    float4 acc = *(const float4*)&h[(size_t)node * HID + c];   // self loop
    acc.x *= s2; acc.y *= s2; acc.z *= s2; acc.w *= s2;

    int j = rowptr[node], end = rowptr[node + 1];
    for (; j + 7 < end; j += 8) {
        int2 e[8];
        float4 hv[8];
#pragma unroll
        for (int u = 0; u < 8; ++u) e[u] = ebuf[j + u];
#pragma unroll
        for (int u = 0; u < 8; ++u)
            hv[u] = *(const float4*)&h[(size_t)e[u].x * HID + c];
#pragma unroll
        for (int u = 0; u < 8; ++u) {
            float w0 = __int_as_float(e[u].y);
            acc.x = fmaf(hv[u].x, w0, acc.x); acc.y = fmaf(hv[u].y, w0, acc.y);
            acc.z = fmaf(hv[u].z, w0, acc.z); acc.w = fmaf(hv[u].w, w0, acc.w);
        }
    }
    for (; j < end; ++j) {
        int2 e0 = ebuf[j];
        float4 h0 = *(const float4*)&h[(size_t)e0.x * HID + c];
        float w0 = __int_as_float(e0.y);
        acc.x = fmaf(h0.x, w0, acc.x); acc.y = fmaf(h0.y, w0, acc.y);
        acc.z = fmaf(h0.z, w0, acc.z); acc.w = fmaf(h0.w, w0, acc.w);
    }

    float4 bv = *(const float4*)&bias[c];
    acc.x = fmaxf(acc.x + bv.x, 0.f);
    acc.y = fmaxf(acc.y + bv.y, 0.f);
    acc.z = fmaxf(acc.z + bv.z, 0.f);
    acc.w = fmaxf(acc.w + bv.w, 0.f);
    *(float4*)&out[(size_t)node * HID + c] = acc;
}

// ---------------- global mean pool (batch sorted) ----------------

__global__ __launch_bounds__(128) void pool_k(const int* __restrict__ batch,
                                              const float* __restrict__ h,
                                              float* __restrict__ pooled, int n) {
    int g = blockIdx.x;
    __shared__ int sh[2];
    if (threadIdx.x < 2) {
        int target = g + (int)threadIdx.x;
        int lo = 0, hi = n;
        while (lo < hi) {
            int mid = (lo + hi) >> 1;
            if (batch[mid] < target) lo = mid + 1; else hi = mid;
        }
        sh[threadIdx.x] = lo;
    }
    __syncthreads();
    int lo = sh[0], hi = sh[1];
    float sum = 0.f;
    for (int i = lo; i < hi; ++i) sum += h[(size_t)i * HID + threadIdx.x];
    float cnt = (float)(hi - lo);
    pooled[(size_t)g * HID + threadIdx.x] = sum / fmaxf(cnt, 1.0f);
}

// ---------------- launch ----------------

extern "C" void kernel_launch(void* const* d_in, const int* in_sizes, int n_in,
                              void* d_out, int out_size, void* d_ws, size_t ws_size,
                              hipStream_t stream) {
    const float* x     = (const float*)d_in[0];
    const int*   ei    = (const int*)d_in[1];
    const int*   batch = (const int*)d_in[2];
    const float* W1    = (const float*)d_in[3];
    const float* b1    = (const float*)d_in[4];
    const float* W2    = (const float*)d_in[5];
    const float* b2    = (const float*)d_in[6];
    const float* Wl    = (const float*)d_in[7];
    const float* bl    = (const float*)d_in[8];

    const int N = in_sizes[0] / IN_CH;
    const int E = in_sizes[1] / 2;

    float* out    = (float*)d_out;
    float* pooled = out + (size_t)N * OUT_CH;

    // ws layout: dinv[N] | cnt[N] | rowptr[N+1] | cursor[N] | bsum[256] | boff[256]
    //            | ebuf[E int2] | bufA[N*128] | bufB[N*128]
    char* w = (char*)d_ws;
    auto align16 = [](size_t s) { return (s + 15) & ~(size_t)15; };
    float* dinv   = (float*)w;                 w += align16((size_t)N * 4);
    int*   cnt    = (int*)w;                   w += align16((size_t)N * 4);
    int*   rowptr = (int*)w;                   w += align16((size_t)(N + 1) * 4);
    int*   cursor = (int*)w;                   w += align16((size_t)N * 4);
    int*   bsum   = (int*)w;                   w += align16(256 * 4);
    int*   boff   = (int*)w;                   w += align16(256 * 4);
    int2*  ebuf   = (int2*)w;                  w += align16((size_t)E * 8);
    float* bufA   = (float*)w;                 w += align16((size_t)N * HID * 4);
    float* bufB   = (float*)w;

    const int nbN = (N + 255) / 256;           // 196 for N=50000 (<=256 for scan_top)
    const int nbE = (E + 255) / 256;
    const int nbG = (N + 7) / 8;               // gather: 8 nodes (half-waves) per block
    const int gb  = (N + 63) / 64;             // gemm blocks

    // CSR build (once, reused by both convs)
    cnt_init_k <<<nbN, 256, 0, stream>>>(cnt, N);
    count_k    <<<nbE, 256, 0, stream>>>(ei, cnt, E);
    dinv_k     <<<nbN, 256, 0, stream>>>(cnt, dinv, N);
    scan_part_k<<<nbN, 256, 0, stream>>>(cnt, bsum, N);
    scan_top_k <<<1,   256, 0, stream>>>(bsum, boff, nbN);
    scan_down_k<<<nbN, 256, 0, stream>>>(cnt, boff, rowptr, cursor, N);
    scatter_k  <<<nbE, 256, 0, stream>>>(ei, dinv, cursor, ebuf, E);

    // conv1
    gemm_k<HID, false><<<gb, 256, 0, stream>>>(x, W1, nullptr, bufA, N);
    gather_k<<<nbG, 256, 0, stream>>>(rowptr, ebuf, dinv, bufA, b1, bufB, N);

    // conv2
    gemm_k<HID, false><<<gb, 256, 0, stream>>>(bufB, W2, nullptr, bufA, N);
    gather_k<<<nbG, 256, 0, stream>>>(rowptr, ebuf, dinv, bufA, b2, bufB, N);

    // head
    gemm_k<OUT_CH, true><<<gb, 256, 0, stream>>>(bufB, Wl, bl, out, N);
    pool_k<<<NGRAPH, 128, 0, stream>>>(batch, bufB, pooled, N);
}